// Round 14
// baseline (122.352 us; speedup 1.0000x reference)
//
#include <hip/hip_runtime.h>

#define HIDDEN 1024
#define NB 8
#define SEQ 2048
#define DH 64

typedef long long i64;
typedef unsigned short u16;
typedef __attribute__((ext_vector_type(8))) _Float16 half8;  // 4 VGPRs = 8 fp16
typedef __attribute__((ext_vector_type(4))) float f32x4;

#define MFMA16F __builtin_amdgcn_mfma_f32_16x16x32_f16

__device__ __forceinline__ u16 f2h(float x) {
    _Float16 h = (_Float16)x;                 // RNE
    return __builtin_bit_cast(u16, h);
}
__device__ __forceinline__ void gl_lds16(const void* g, void* l) {
    __builtin_amdgcn_global_load_lds(
        (const __attribute__((address_space(1))) unsigned int*)g,
        (__attribute__((address_space(3))) unsigned int*)l, 16, 0, 0);
}

// ---------------------------------------------------------------------------
// Prepass: W[1024][64] (x3) -> Wimg[te][p][n][pos] fp16, p = 16 phases of
// BK=64, n = out col, pos = 16B block (8 per row); position pos holds global
// k-chunk (pos ^ (n&7)). Contiguous in staging order; XOR pre-swizzle makes
// proj's ds_reads 2-way (free).
// ---------------------------------------------------------------------------
__global__ __launch_bounds__(256) void wimg_prep16(
    const float* __restrict__ Wq, const float* __restrict__ Wk, const float* __restrict__ Wv,
    u16* __restrict__ Wimg)
{
    const int t = blockIdx.x * 256 + threadIdx.x;   // 24576 threads
    const int te = t >> 13;
    const int rem = t & 8191;
    const int p = rem >> 9;                          // 0..15
    const int rem2 = rem & 511;
    const int n = rem2 >> 3;                         // 0..63
    const int pos = rem2 & 7;                        // 16B block in row
    const float* W = te == 0 ? Wq : te == 1 ? Wk : Wv;
    const int g = pos ^ (n & 7);
    const int k0 = p * 64 + g * 8;
    u16* dst = Wimg + (i64)t * 8;
    #pragma unroll
    for (int j = 0; j < 8; ++j)
        dst[j] = f2h(W[(i64)(k0 + j) * DH + n]);
}

// ---------------------------------------------------------------------------
// Projection v9: issue-early double-buffered pipeline (attn-style ordering).
// Block = 128 thr = 2 waves, tile 32 rows x 64 cols; wave w owns rows w*16..
// Grid (512, 3) = 1536 blocks -> 6 blocks/CU, 12 waves/CU.
// K in 16 phases of BK=64. Per phase: __syncthreads() drains the stage that
// was issued ONE FULL COMPUTE PHASE ago (not zero instructions ago, v8's
// bug), then issue W(p+1) gl_lds + A(p+1) reg loads, then compute(p):
// 2 ks x [cvt 8 fp32->half8 ; 4 x (ds_read b128 (2-way, free) + MFMA)].
// ---------------------------------------------------------------------------
__global__ __launch_bounds__(128) void proj_mfma9(
    const float* __restrict__ qh, const float* __restrict__ kh, const float* __restrict__ vh,
    const u16* __restrict__ Wimg,
    const float* __restrict__ bq, const float* __restrict__ bk, const float* __restrict__ bv,
    u16* __restrict__ Qb, u16* __restrict__ Kb, u16* __restrict__ Vt)
{
    const int te = blockIdx.y;
    const float* A    = te == 0 ? qh : te == 1 ? kh : vh;
    const float* bias = te == 0 ? bq : te == 1 ? bk : bv;
    const int row0 = blockIdx.x << 5;          // 512 tiles of 32 rows
    const int t = threadIdx.x;
    const int w = t >> 6, lane = t & 63;
    const int lr = lane & 15, lg = lane >> 4;

    __shared__ __attribute__((aligned(16))) u16 WL[2][4096];   // 8KB per buf

    const u16* Wte = Wimg + (i64)te * 16 * 4096;
    const float* arow = A + (i64)(row0 + w * 16 + lr) * HIDDEN + (lg << 3);

    f32x4 acc[4] = {};

    // stage W phase P into buffer B: 4 x 1KB gl_lds per wave (linear)
#define STAGEW(P, B) { \
        _Pragma("unroll") \
        for (int i_ = 0; i_ < 4; ++i_) { \
            const int off_ = ((w << 2) + i_) << 9; \
            gl_lds16(Wte + ((P) << 12) + off_ + (lane << 3), &WL[B][off_ + (lane << 3) - (lane << 3)] + off_ * 0 + 0); \
        } }
    // (note: dst must be wave-uniform; rewritten explicitly below)
#undef STAGEW
#define STAGEW(P, B) { \
        _Pragma("unroll") \
        for (int i_ = 0; i_ < 4; ++i_) { \
            const int off_ = ((w << 2) + i_) << 9; \
            gl_lds16(Wte + ((P) << 12) + off_ + (lane << 3), &WL[B][off_]); \
        } }

#define LOADA(P, r00, r01, r10, r11) { \
        const int kb_ = ((P) & 15) << 6; \
        r00 = *(const float4*)(arow + kb_); \
        r01 = *(const float4*)(arow + kb_ + 4); \
        r10 = *(const float4*)(arow + kb_ + 32); \
        r11 = *(const float4*)(arow + kb_ + 36); }

#define COMPUTE(B, r00, r01, r10, r11) { \
        half8 a0_, a1_; \
        a0_[0] = (_Float16)r00.x; a0_[1] = (_Float16)r00.y; \
        a0_[2] = (_Float16)r00.z; a0_[3] = (_Float16)r00.w; \
        a0_[4] = (_Float16)r01.x; a0_[5] = (_Float16)r01.y; \
        a0_[6] = (_Float16)r01.z; a0_[7] = (_Float16)r01.w; \
        a1_[0] = (_Float16)r10.x; a1_[1] = (_Float16)r10.y; \
        a1_[2] = (_Float16)r10.z; a1_[3] = (_Float16)r10.w; \
        a1_[4] = (_Float16)r11.x; a1_[5] = (_Float16)r11.y; \
        a1_[6] = (_Float16)r11.z; a1_[7] = (_Float16)r11.w; \
        _Pragma("unroll") \
        for (int nt_ = 0; nt_ < 4; ++nt_) { \
            const int n_ = nt_ * 16 + lr; \
            const half8 b0_ = *(const half8*)&WL[B][n_ * 64 + (((lg) ^ (n_ & 7)) << 3)]; \
            acc[nt_] = MFMA16F(a0_, b0_, acc[nt_], 0, 0, 0); \
        } \
        _Pragma("unroll") \
        for (int nt_ = 0; nt_ < 4; ++nt_) { \
            const int n_ = nt_ * 16 + lr; \
            const half8 b1_ = *(const half8*)&WL[B][n_ * 64 + ((((4 + lg)) ^ (n_ & 7)) << 3)]; \
            acc[nt_] = MFMA16F(a1_, b1_, acc[nt_], 0, 0, 0); \
        } }

    float4 e00, e01, e10, e11, o00, o01, o10, o11;

    // prologue: stage phase 0 (buf0) + A(0) into even regs
    STAGEW(0, 0)
    LOADA(0, e00, e01, e10, e11)

    #pragma unroll 1
    for (int p2 = 0; p2 < 16; p2 += 2) {
        // ---- even phase p2 (buf0, even regs) ----
        __syncthreads();                        // drains stage(p2) + A(p2)
        STAGEW((p2 + 1) & 15, 1)                // issue next stage early
        LOADA(p2 + 1, o00, o01, o10, o11)
        COMPUTE(0, e00, e01, e10, e11)
        // ---- odd phase p2+1 (buf1, odd regs) ----
        __syncthreads();                        // drains stage(p2+1) + A(p2+1)
        STAGEW((p2 + 2) & 15, 0)
        LOADA(p2 + 2, e00, e01, e10, e11)
        COMPUTE(1, o00, o01, o10, o11)
    }
#undef STAGEW
#undef LOADA
#undef COMPUTE

    // epilogue: D layout col=lane&15 (within nt), row=(lane>>4)*4+reg
    #pragma unroll
    for (int nt = 0; nt < 4; ++nt) {
        const int col = nt * 16 + lr;
        const float bb = bias[col];
        #pragma unroll
        for (int r = 0; r < 4; ++r) {
            const i64 grow = row0 + w * 16 + (lg << 2) + r;
            const u16 v = f2h(acc[nt][r] + bb);
            if (te == 0)      Qb[grow * DH + col] = v;
            else if (te == 1) Kb[grow * DH + col] = v;
            else {
                const i64 bb2 = grow >> 11, key = grow & 2047;
                Vt[(bb2 * DH + col) * SEQ + key] = v;
            }
        }
    }
}

// ---------------------------------------------------------------------------
// Attention: 1024 single-wave blocks (16 q-rows each), no barriers.
// (byte-identical to the round-13 passing fp16 version)
// ---------------------------------------------------------------------------
__global__ __launch_bounds__(64) void attn_mfma(
    const u16* __restrict__ Qb, const u16* __restrict__ Kb, const u16* __restrict__ Vt,
    const int* __restrict__ mask, float* __restrict__ out)
{
    __shared__ __attribute__((aligned(16))) u16 Kl[2][64 * 64];
    __shared__ __attribute__((aligned(16))) u16 Vl[2][64 * 64];
    __shared__ __attribute__((aligned(16))) u16 Pl[16][72];

    const int lane = threadIdx.x;
    const int lr = lane & 15, lg = lane >> 4;
    const int b  = blockIdx.x >> 7;
    const int q0 = (blockIdx.x & 127) << 4;

    const i64 qrow = (i64)b * SEQ + q0 + lr;
    const half8 qf0 = *(const half8*)(Qb + qrow * DH + lg * 8);
    const half8 qf1 = *(const half8*)(Qb + qrow * DH + 32 + lg * 8);

    const int srow = lane >> 3;   // 0..7 (+8i)
    const int scb  = lane & 7;    // 16B block

    f32x4 oacc[4] = {};
    float rs0 = 0.f, rs1 = 0.f, rs2 = 0.f, rs3 = 0.f;

    // prologue: stage tile 0 into buf 0 (16 loads)
    {
        const i64 kbase = (i64)b * SEQ;
        #pragma unroll
        for (int i = 0; i < 8; ++i) {
            int row = i * 8 + srow, cb = scb ^ (row & 7);
            gl_lds16(Kb + (kbase + row) * DH + cb * 8, &Kl[0][i * 512]);
        }
        #pragma unroll
        for (int i = 0; i < 8; ++i) {
            int row = i * 8 + srow, cb = scb ^ (row & 7);
            gl_lds16(Vt + ((i64)b * DH + row) * SEQ + cb * 8, &Vl[0][i * 512]);
        }
    }

    #pragma unroll 1
    for (int t = 0; t < 32; ++t) {
        const int kt = t * 64;
        const int buf = t & 1;

        int mv[16];
        #pragma unroll
        for (int tt = 0; tt < 4; ++tt)
            #pragma unroll
            for (int r = 0; r < 4; ++r)
                mv[tt * 4 + r] =
                    mask[((i64)b * SEQ + q0 + lg * 4 + r) * SEQ + kt + tt * 16 + lr];

        if (t < 31) {
            const int kn = kt + 64;
            const i64 kbase = (i64)b * SEQ + kn;
            #pragma unroll
            for (int i = 0; i < 8; ++i) {
                int row = i * 8 + srow, cb = scb ^ (row & 7);
                gl_lds16(Kb + (kbase + row) * DH + cb * 8, &Kl[buf ^ 1][i * 512]);
            }
            #pragma unroll
            for (int i = 0; i < 8; ++i) {
                int row = i * 8 + srow, cb = scb ^ (row & 7);
                gl_lds16(Vt + ((i64)b * DH + row) * SEQ + kn + cb * 8, &Vl[buf ^ 1][i * 512]);
            }
            asm volatile("s_waitcnt vmcnt(32)" ::: "memory");
        } else {
            asm volatile("s_waitcnt vmcnt(16)" ::: "memory");
        }

        f32x4 sacc[4] = {};
        #pragma unroll
        for (int tt = 0; tt < 4; ++tt) {
            int row = tt * 16 + lr, x = row & 7;
            half8 k0 = *(const half8*)&Kl[buf][row * 64 + ((lg) ^ x) * 8];
            half8 k1 = *(const half8*)&Kl[buf][row * 64 + ((lg + 4) ^ x) * 8];
            sacc[tt] = MFMA16F(qf0, k0, sacc[tt], 0, 0, 0);
            sacc[tt] = MFMA16F(qf1, k1, sacc[tt], 0, 0, 0);
        }

        #pragma unroll
        for (int tt = 0; tt < 4; ++tt) {
            #pragma unroll
            for (int r = 0; r < 4; ++r) {
                float p = (mv[tt * 4 + r] != 0) ? __expf(sacc[tt][r] * 0.125f) : 0.0f;
                if      (r == 0) rs0 += p;
                else if (r == 1) rs1 += p;
                else if (r == 2) rs2 += p;
                else             rs3 += p;
                Pl[lg * 4 + r][tt * 16 + lr] = f2h(p);
            }
        }

        const half8 p0 = *(const half8*)&Pl[lr][lg * 8];
        const half8 p1 = *(const half8*)&Pl[lr][32 + lg * 8];
        #pragma unroll
        for (int vt = 0; vt < 4; ++vt) {
            int row = vt * 16 + lr, x = row & 7;
            half8 v0 = *(const half8*)&Vl[buf][row * 64 + ((lg) ^ x) * 8];
            half8 v1 = *(const half8*)&Vl[buf][row * 64 + ((lg + 4) ^ x) * 8];
            oacc[vt] = MFMA16F(p0, v0, oacc[vt], 0, 0, 0);
            oacc[vt] = MFMA16F(p1, v1, oacc[vt], 0, 0, 0);
        }
    }

    float rs[4] = {rs0, rs1, rs2, rs3};
    #pragma unroll
    for (int r = 0; r < 4; ++r) {
        float v = rs[r];
        v += __shfl_xor(v, 1, 64);
        v += __shfl_xor(v, 2, 64);
        v += __shfl_xor(v, 4, 64);
        v += __shfl_xor(v, 8, 64);
        rs[r] = 1.0f / v;
    }
    #pragma unroll
    for (int vt = 0; vt < 4; ++vt)
        #pragma unroll
        for (int r = 0; r < 4; ++r)
            out[((i64)b * SEQ + q0 + lg * 4 + r) * DH + vt * 16 + lr] = oacc[vt][r] * rs[r];
}

extern "C" void kernel_launch(void* const* d_in, const int* in_sizes, int n_in,
                              void* d_out, int out_size, void* d_ws, size_t ws_size,
                              hipStream_t stream) {
    const float* kh   = (const float*)d_in[0];
    const float* qh   = (const float*)d_in[1];
    const float* vh   = (const float*)d_in[2];
    const int*   mask = (const int*)  d_in[3];
    const float* Wq   = (const float*)d_in[4];
    const float* bq   = (const float*)d_in[5];
    const float* Wk   = (const float*)d_in[6];
    const float* bk   = (const float*)d_in[7];
    const float* Wv   = (const float*)d_in[8];
    const float* bv   = (const float*)d_in[9];
    float* out = (float*)d_out;

    u16* Wimg = (u16*)d_ws;                      // 3*16*4096 u16 = 384 KB
    u16* Qb   = Wimg + 3 * 16 * 4096;            // 2 MB each
    u16* Kb   = Qb + (i64)NB * SEQ * DH;
    u16* Vt   = Kb + (i64)NB * SEQ * DH;         // [b][vd][key]

    wimg_prep16<<<96, 256, 0, stream>>>(Wq, Wk, Wv, Wimg);
    proj_mfma9<<<dim3(512, 3), 128, 0, stream>>>(qh, kh, vh, Wimg,
                                                 bq, bk, bv, Qb, Kb, Vt);
    attn_mfma<<<1024, 64, 0, stream>>>(Qb, Kb, Vt, mask, out);
}